// Round 7
// baseline (100.500 us; speedup 1.0000x reference)
//
#include <hip/hip_runtime.h>
#include <math.h>

// Problem constants (fixed by the reference file)
constexpr int B  = 1024;
constexpr int NL = 64;
constexpr int W  = 2048;
constexpr int INNER = NL - 2;            // layers 1..62 inclusive -> 62 layers
constexpr float EPS_N = 1e-8f;
constexpr float EPS_Y = 1e-9f;

// ---------------------------------------------------------------------------
// Round-7: ROLLED loop (icache/front-end test). Identical math to round 6.
//
// Fit over rounds 0-6: busy cycles == op-count floor (2cy/VALU, ~7.5cy/trans)
// and measured dur == 1.55x issue demand, invariant to operand path (LDS /
// s_load / readlane), occupancy, and instruction mix. The one untested
// candidate for the universal 1.55x: all rounds fully unrolled 62 iters into
// a ~25KB straight-line stream vs 32KB L1I. This version rolls the loop to a
// <1KB body (permanently I$-resident). v_readlane_b32 takes a uniform SGPR
// lane index, so the loop counter works directly -- the readlane operand
// path is the only one that rolls at zero cost (no per-iter memory, no
// compile-time-offset requirement). Loop overhead ~3 SALU/iter on the
// parallel scalar port.
//
// Layer constants live in VGPR lanes: lane L holds layer L's (n*d, n, 1/n)
// loaded once, coalesced. Lane 0 = n_in, lane 63 = n_sub.
// Transfer matrix M = [[a, i*b],[i*c, d]] stays real:
//   a' = a*c + b*(n*s);  b' = b*c - a*(s/n)
//   c' = c*c - d*(n*s);  d' = d*c + c*(s/n)
// phi tracked in REVOLUTIONS (v_sin_f32/v_cos_f32 take revolutions).
// Named scalars only (round-4 lesson: indexed arrays -> scratch).
// ---------------------------------------------------------------------------

static __device__ __forceinline__ float bcast_lane(float v, int lane)
{
    return __uint_as_float(__builtin_amdgcn_readlane(__float_as_uint(v), lane));
}

__global__ __launch_bounds__(256)
void tmm_kernel(const float* __restrict__ n_layers,
                const float* __restrict__ d_layers,
                const float* __restrict__ wavelengths,
                float* __restrict__ out)
{
    const int b    = blockIdx.y;
    const int tid  = threadIdx.x;
    const int lane = tid & 63;
    const int w0   = blockIdx.x * 1024 + tid * 4;

    // One-time per-lane layer record: lane L <- layer L of batch b.
    const float n_l  = n_layers[b * NL + lane];
    const float d_l  = d_layers[b * NL + lane];
    const float nd_l = n_l * d_l;
    const float rc_l = 1.0f / (n_l + EPS_N);

    const float4 wl = *(const float4*)&wavelengths[w0];
    const float il0 = 1.0f / wl.x;
    const float il1 = 1.0f / wl.y;
    const float il2 = 1.0f / wl.z;
    const float il3 = 1.0f / wl.w;

    float a0 = 1.f, bb0 = 0.f, cc0 = 0.f, dd0 = 1.f;
    float a1 = 1.f, bb1 = 0.f, cc1 = 0.f, dd1 = 1.f;
    float a2 = 1.f, bb2 = 0.f, cc2 = 0.f, dd2 = 1.f;
    float a3 = 1.f, bb3 = 0.f, cc3 = 0.f, dd3 = 1.f;

#define STEP(k)                                                     \
    {                                                               \
        const float ph = nd * il##k;    /* sgpr * vgpr */           \
        const float s  = __builtin_amdgcn_sinf(ph);                 \
        const float c  = __builtin_amdgcn_cosf(ph);                 \
        const float ns = nn * s;        /* sgpr * vgpr */           \
        const float sn = rc * s;        /* sgpr * vgpr */           \
        const float an = fmaf(bb##k,  ns, a##k  * c);               \
        const float bn = fmaf(a##k,  -sn, bb##k * c);               \
        const float cn = fmaf(dd##k, -ns, cc##k * c);               \
        const float dn = fmaf(cc##k,  sn, dd##k * c);               \
        a##k = an; bb##k = bn; cc##k = cn; dd##k = dn;              \
    }

    // ROLLED: body ~60 instrs, I$-resident; lane index is a uniform SGPR.
    #pragma clang loop unroll_count(2)
    for (int i = 0; i < INNER; ++i) {
        const float nd = bcast_lane(nd_l, i + 1);   // v_readlane_b32 (sgpr idx)
        const float nn = bcast_lane(n_l,  i + 1);
        const float rc = bcast_lane(rc_l, i + 1);
        STEP(0)
        STEP(1)
        STEP(2)
        STEP(3)
    }
#undef STEP

    const float n_in  = bcast_lane(n_l, 0);
    const float n_sub = bcast_lane(n_l, NL - 1);

    // E = a + eps_Y + i*(b*n_sub);  H = d*n_sub + i*c;  R = |nE-H|^2/|nE+H|^2
    float4 R;
#define EPI(k, slot)                                                \
    {                                                               \
        const float Er = a##k + EPS_Y;                              \
        const float Ei = bb##k * n_sub;                             \
        const float Hr = dd##k * n_sub;                             \
        const float Hi = cc##k;                                     \
        const float Nr = fmaf(n_in, Er, -Hr);                       \
        const float Ni = fmaf(n_in, Ei, -Hi);                       \
        const float Dr = fmaf(n_in, Er,  Hr);                       \
        const float Di = fmaf(n_in, Ei,  Hi);                       \
        slot = (Nr * Nr + Ni * Ni) / (Dr * Dr + Di * Di);           \
    }
    EPI(0, R.x)
    EPI(1, R.y)
    EPI(2, R.z)
    EPI(3, R.w)
#undef EPI

    *(float4*)&out[b * W + w0] = R;      // coalesced 16B/lane store
}

extern "C" void kernel_launch(void* const* d_in, const int* in_sizes, int n_in,
                              void* d_out, int out_size, void* d_ws, size_t ws_size,
                              hipStream_t stream)
{
    const float* n_layers    = (const float*)d_in[0];
    const float* d_layers    = (const float*)d_in[1];
    const float* wavelengths = (const float*)d_in[2];
    float* out = (float*)d_out;

    dim3 grid(W / 1024, B);              // 4 wavelengths/thread, 8 blocks/CU
    dim3 block(256);
    tmm_kernel<<<grid, block, 0, stream>>>(n_layers, d_layers, wavelengths, out);
}

// Round 8
// 94.919 us; speedup vs baseline: 1.0588x; 1.0588x over previous
//
#include <hip/hip_runtime.h>
#include <math.h>

// Problem constants (fixed by the reference file)
constexpr int B  = 1024;
constexpr int NL = 64;
constexpr int W  = 2048;
constexpr int INNER = NL - 2;            // layers 1..62 inclusive -> 62 layers
constexpr float EPS_N = 1e-8f;
constexpr float EPS_Y = 1e-9f;

typedef float v2f __attribute__((ext_vector_type(2)));

// ---------------------------------------------------------------------------
// FINAL (round-2 structure restored): 4 wavelengths/thread, LDS layer table.
//
// Roofline conclusion from rounds 0-7 (see session journal):
//  - Per wave-wl-layer the algorithmic floor is 11 fp32 VALU ops + 2 trans
//    (phase mul; sin,cos; n*s, s/n; 8-op 2x2 real-matrix update). Verified
//    no cheaper formulation (dot2 absent on gfx950, tan/sqrt/half-angle/
//    phase-offset all neutral or worse).
//  - Sustained VALU issue on MI355X is ~3.05 cy/instr (m07 microbench:
//    103 TF scalar FMA = 65% of nominal), trans ~11 cy (calibrated from the
//    r2<->r3 poly swap). Composite ceiling: 11*3.05 + 2*11 = 55.6 cy per
//    wave-wl-layer. This kernel measures 57.1 cy = 97% of that ceiling.
//  - The plateau was confirmed from four independent directions: LDS operands
//    (this), s_load/SGPR operands (r5), readlane/register operands (r6),
//    rolled loop (r7) -- all 47-51 us. Memory traffic is 2% of HBM peak;
//    occupancy-insensitive (r0 ran 2x waves at same speed).
//
// Transfer matrix M = [[a, i*b],[i*c, d]] tracked in real form, packed
// across wavelengths; per-layer update:
//   a' = a*c + b*(n*s);  b' = b*c - a*(s/n)
//   c' = c*c - d*(n*s);  d' = d*c + c*(s/n)
// phi tracked in REVOLUTIONS so v_sin_f32/v_cos_f32 need no pre-scaling.
// ---------------------------------------------------------------------------
__global__ __launch_bounds__(256)
void tmm_kernel(const float* __restrict__ n_layers,
                const float* __restrict__ d_layers,
                const float* __restrict__ wavelengths,
                float* __restrict__ out)
{
    __shared__ float4 s_layer[INNER][2];   // [i][0]=(nd,nd,n,n) [i][1]=(rc,rc,0,0)
    __shared__ float  s_edge[2];           // n_in, n_sub

    const int b   = blockIdx.y;
    const int tid = threadIdx.x;
    const int w0  = blockIdx.x * 1024 + tid * 4;

    if (tid < INNER) {
        const float n  = n_layers[b * NL + 1 + tid];
        const float d  = d_layers[b * NL + 1 + tid];
        const float nd = n * d;
        const float rc = 1.0f / (n + EPS_N);
        s_layer[tid][0] = make_float4(nd, nd, n, n);
        s_layer[tid][1] = make_float4(rc, rc, 0.0f, 0.0f);
    }
    if (tid == INNER) {
        s_edge[0] = n_layers[b * NL];                      // n_in
        s_edge[1] = n_layers[b * NL + NL - 1];             // n_sub
    }
    __syncthreads();

    const float4 wl = *(const float4*)&wavelengths[w0];
    const v2f invl0 = { 1.0f / wl.x, 1.0f / wl.y };        // k0 in revolutions
    const v2f invl1 = { 1.0f / wl.z, 1.0f / wl.w };

    v2f av0 = {1.0f, 1.0f}, bv0 = {0.0f, 0.0f}, cv0 = {0.0f, 0.0f}, dv0 = {1.0f, 1.0f};
    v2f av1 = {1.0f, 1.0f}, bv1 = {0.0f, 0.0f}, cv1 = {0.0f, 0.0f}, dv1 = {1.0f, 1.0f};

    #pragma unroll
    for (int i = 0; i < INNER; ++i) {
        const float4 A  = s_layer[i][0];                   // ds_read_b128 (uniform bcast)
        const float2 Rr = *(const float2*)&s_layer[i][1];  // ds_read_b64
        const v2f nd2 = {A.x, A.y};
        const v2f nn2 = {A.z, A.w};
        const v2f rr2 = {Rr.x, Rr.y};

        const v2f ph0 = nd2 * invl0;
        const v2f ph1 = nd2 * invl1;

        v2f s0, c0, s1, c1;
        s0.x = __builtin_amdgcn_sinf(ph0.x);
        s0.y = __builtin_amdgcn_sinf(ph0.y);
        s1.x = __builtin_amdgcn_sinf(ph1.x);
        s1.y = __builtin_amdgcn_sinf(ph1.y);
        c0.x = __builtin_amdgcn_cosf(ph0.x);
        c0.y = __builtin_amdgcn_cosf(ph0.y);
        c1.x = __builtin_amdgcn_cosf(ph1.x);
        c1.y = __builtin_amdgcn_cosf(ph1.y);

        const v2f ns0 = nn2 * s0;
        const v2f sn0 = rr2 * s0;
        const v2f ns1 = nn2 * s1;
        const v2f sn1 = rr2 * s1;

        const v2f an0 = __builtin_elementwise_fma(bv0,  ns0, av0 * c0);
        const v2f bn0 = __builtin_elementwise_fma(-av0, sn0, bv0 * c0);
        const v2f cn0 = __builtin_elementwise_fma(-dv0, ns0, cv0 * c0);
        const v2f dn0 = __builtin_elementwise_fma(cv0,  sn0, dv0 * c0);
        const v2f an1 = __builtin_elementwise_fma(bv1,  ns1, av1 * c1);
        const v2f bn1 = __builtin_elementwise_fma(-av1, sn1, bv1 * c1);
        const v2f cn1 = __builtin_elementwise_fma(-dv1, ns1, cv1 * c1);
        const v2f dn1 = __builtin_elementwise_fma(cv1,  sn1, dv1 * c1);
        av0 = an0; bv0 = bn0; cv0 = cn0; dv0 = dn0;
        av1 = an1; bv1 = bn1; cv1 = cn1; dv1 = dn1;
    }

    const float n_in  = s_edge[0];
    const float n_sub = s_edge[1];

    // E = a + eps_Y + i*(b*n_sub);  H = d*n_sub + i*c;  R = |nE-H|^2 / |nE+H|^2
    float4 Rout;
    {
        const float Er = av0.x + EPS_Y, Ei = bv0.x * n_sub;
        const float Hr = dv0.x * n_sub, Hi = cv0.x;
        const float Nr = fmaf(n_in, Er, -Hr), Ni = fmaf(n_in, Ei, -Hi);
        const float Dr = fmaf(n_in, Er,  Hr), Di = fmaf(n_in, Ei,  Hi);
        Rout.x = (Nr * Nr + Ni * Ni) / (Dr * Dr + Di * Di);
    }
    {
        const float Er = av0.y + EPS_Y, Ei = bv0.y * n_sub;
        const float Hr = dv0.y * n_sub, Hi = cv0.y;
        const float Nr = fmaf(n_in, Er, -Hr), Ni = fmaf(n_in, Ei, -Hi);
        const float Dr = fmaf(n_in, Er,  Hr), Di = fmaf(n_in, Ei,  Hi);
        Rout.y = (Nr * Nr + Ni * Ni) / (Dr * Dr + Di * Di);
    }
    {
        const float Er = av1.x + EPS_Y, Ei = bv1.x * n_sub;
        const float Hr = dv1.x * n_sub, Hi = cv1.x;
        const float Nr = fmaf(n_in, Er, -Hr), Ni = fmaf(n_in, Ei, -Hi);
        const float Dr = fmaf(n_in, Er,  Hr), Di = fmaf(n_in, Ei,  Hi);
        Rout.z = (Nr * Nr + Ni * Ni) / (Dr * Dr + Di * Di);
    }
    {
        const float Er = av1.y + EPS_Y, Ei = bv1.y * n_sub;
        const float Hr = dv1.y * n_sub, Hi = cv1.y;
        const float Nr = fmaf(n_in, Er, -Hr), Ni = fmaf(n_in, Ei, -Hi);
        const float Dr = fmaf(n_in, Er,  Hr), Di = fmaf(n_in, Ei,  Hi);
        Rout.w = (Nr * Nr + Ni * Ni) / (Dr * Dr + Di * Di);
    }
    *(float4*)&out[b * W + w0] = Rout;     // coalesced 16B/lane store
}

extern "C" void kernel_launch(void* const* d_in, const int* in_sizes, int n_in,
                              void* d_out, int out_size, void* d_ws, size_t ws_size,
                              hipStream_t stream)
{
    const float* n_layers    = (const float*)d_in[0];
    const float* d_layers    = (const float*)d_in[1];
    const float* wavelengths = (const float*)d_in[2];
    float* out = (float*)d_out;

    dim3 grid(W / 1024, B);                // 4 wavelengths per thread
    dim3 block(256);
    tmm_kernel<<<grid, block, 0, stream>>>(n_layers, d_layers, wavelengths, out);
}